// Round 4
// baseline (278.614 us; speedup 1.0000x reference)
//
#include <hip/hip_runtime.h>
#include <hip/hip_bf16.h>

typedef __bf16 bf16x8 __attribute__((ext_vector_type(8)));
typedef float  float4v __attribute__((ext_vector_type(4)));
typedef unsigned short u16;
typedef u16 u16x8 __attribute__((ext_vector_type(8)));

#define NB 32
#define NT 2048
#define ND 512
#define NU 512
#define BK 32        // K per phase; 16 phases, double-buffered

__device__ __forceinline__ u16 f2bf(float f) {
    union { float f; unsigned u; } v; v.f = f;
    unsigned u = v.u;
    return (u16)((u + 0x7fffu + ((u >> 16) & 1u)) >> 16);  // RNE
}

__device__ __forceinline__ u16x8 cvt8(float4v a, float4v b) {
    union { __hip_bfloat162 h[4]; u16x8 v; } u;
    u.h[0] = __float22bfloat162_rn(make_float2(a[0], a[1]));
    u.h[1] = __float22bfloat162_rn(make_float2(a[2], a[3]));
    u.h[2] = __float22bfloat162_rn(make_float2(b[0], b[1]));
    u.h[3] = __float22bfloat162_rn(make_float2(b[2], b[3]));
    return u.v;
}

__device__ __forceinline__ float fast_tanh(float x) {
    float e = __expf(-2.f * x);
    return 2.f / (1.f + e) - 1.f;
}

// ---- setup: W1->bf16 W1^T, projh, and zero logits/ctx ----------------------
__global__ void k_setup(const float* __restrict__ W1, u16* __restrict__ w1t,
                        const float* __restrict__ hidden, const float* __restrict__ W2,
                        const float* __restrict__ b2, float* __restrict__ projh,
                        float* __restrict__ logits, float* __restrict__ ctx) {
    __shared__ u16 tile[32][33];
    __shared__ float h[ND];
    __shared__ float part[4][64];
    if (threadIdx.x < 128) logits[blockIdx.x * 128 + threadIdx.x] = 0.f;
    else if (threadIdx.x < 160) ctx[blockIdx.x * 32 + (threadIdx.x - 128)] = 0.f;

    if (blockIdx.x < 256) {
        int bd = (blockIdx.x & 15) * 32;
        int bu = (blockIdx.x >> 4) * 32;
        int tx = threadIdx.x & 31, ty = threadIdx.x >> 5;
        #pragma unroll
        for (int i = 0; i < 4; ++i)
            tile[ty + i * 8][tx] = f2bf(W1[(bd + ty + i * 8) * NU + bu + tx]);
        __syncthreads();
        #pragma unroll
        for (int i = 0; i < 4; ++i)
            w1t[(bu + ty + i * 8) * ND + bd + tx] = tile[tx][ty + i * 8];
    } else {
        int blk = blockIdx.x - 256;
        int b  = blk >> 3;
        int uc = (blk & 7) * 64;
        int ui = threadIdx.x & 63;
        int du = threadIdx.x >> 6;
        for (int i = threadIdx.x; i < ND; i += 256) h[i] = hidden[b * ND + i];
        __syncthreads();
        int u = uc + ui;
        float acc = 0.f;
        int d0 = du * 128;
        #pragma unroll 8
        for (int d = 0; d < 128; ++d) acc += h[d0 + d] * W2[(d0 + d) * NU + u];
        part[du][ui] = acc;
        __syncthreads();
        if (threadIdx.x < 64)
            projh[b * NU + u] = part[0][ui] + part[1][ui] + part[2][ui] + part[3][ui] + b2[u];
    }
}

// ---- logits partial: block = 128 rows x 256 U, full K=512, pipelined -------
// 4 waves, wave owns 128 rows x 64 cols (mt=8, nt=4, acc=128 VGPR).
// BK=32 double-buffered: loads for p+1 issued before MFMA on p; 1 barrier/phase.
__global__ __launch_bounds__(256, 2)
void k_logits(const float* __restrict__ feat, const u16* __restrict__ w1t,
              const float* __restrict__ b1, const float* __restrict__ projh,
              const float* __restrict__ V, float* __restrict__ logits) {
    __shared__ __align__(16) u16 aT[2][128 * BK];   // 2 x 8 KB
    __shared__ __align__(16) u16 bT[2][256 * BK];   // 2 x 16 KB  (48 KB total)

    const int mtile = blockIdx.x & 511;
    const int utile = blockIdx.x >> 9;           // 0..1
    const int row0  = mtile * 128;
    const int uc    = utile * 256;
    const int b     = row0 >> 11;                // 128 | 2048
    const int tid   = threadIdx.x;
    const int wave  = tid >> 6, lane = tid & 63;
    const int quad  = lane >> 4, col = lane & 15;

    float4v acc[8][4];
    #pragma unroll
    for (int mt = 0; mt < 8; ++mt)
        #pragma unroll
        for (int nt = 0; nt < 4; ++nt) acc[mt][nt] = (float4v)0.f;

    const float* fbase = feat + (long)row0 * ND;
    const u16*   wbase = w1t + uc * ND;

    // B stage: slot s holds 16B; LDS chunk (s&3) of row (s>>2) = global chunk (s&3)^(r&3)
    auto stageB = [&](int p, int buf) {
        const int k0 = p * BK;
        #pragma unroll
        for (int j = 0; j < 4; ++j) {
            int s  = j * 256 + tid;
            int r  = s >> 2;
            int gc = (s & 3) ^ (r & 3);
            const u16* gp = wbase + (long)r * ND + k0 + gc * 8;
            u16* lp = &bT[buf][(j * 256 + wave * 64) * 8];    // wave-uniform base
            __builtin_amdgcn_global_load_lds(
                (const __attribute__((address_space(1))) unsigned int*)gp,
                (__attribute__((address_space(3))) unsigned int*)lp, 16, 0, 0);
        }
    };
    // A stage: 128 rows x 32 k fp32 -> bf16, swizzled chunks
    auto stageA = [&](int p, int buf) {
        const int k0 = p * BK;
        #pragma unroll
        for (int i = 0; i < 2; ++i) {
            int g = tid + i * 256;
            int r = g >> 2, c = g & 3;
            const float* gp = fbase + (long)r * ND + k0 + c * 8;
            float4v f0 = *(const float4v*)gp;
            float4v f1 = *(const float4v*)(gp + 4);
            *(u16x8*)(&aT[buf][r * BK + ((c ^ (r & 3)) * 8)]) = cvt8(f0, f1);
        }
    };

    stageB(0, 0);
    stageA(0, 0);
    __syncthreads();

    for (int p = 0; p < 16; ++p) {
        const int buf = p & 1;
        if (p < 15) {            // prefetch next phase into the other buffer
            stageB(p + 1, buf ^ 1);
            stageA(p + 1, buf ^ 1);
        }
        bf16x8 af[8], bf[4];
        #pragma unroll
        for (int mt = 0; mt < 8; ++mt) {
            int ra = mt * 16 + col;
            af[mt] = *(const bf16x8*)(&aT[buf][ra * BK + ((quad ^ (ra & 3)) * 8)]);
        }
        #pragma unroll
        for (int nt = 0; nt < 4; ++nt) {
            int rb = wave * 64 + nt * 16 + col;
            bf[nt] = *(const bf16x8*)(&bT[buf][rb * BK + ((quad ^ (rb & 3)) * 8)]);
        }
        #pragma unroll
        for (int nt = 0; nt < 4; ++nt)
            #pragma unroll
            for (int mt = 0; mt < 8; ++mt)
                acc[mt][nt] = __builtin_amdgcn_mfma_f32_16x16x32_bf16(af[mt], bf[nt], acc[mt][nt], 0, 0, 0);
        __syncthreads();
    }

    // ---- epilogue: u = uc + wave*64 + nt*16 + col; partial logit per row
    float b1v[4], phv[4], Vv[4];
    #pragma unroll
    for (int nt = 0; nt < 4; ++nt) {
        int u = uc + wave * 64 + nt * 16 + col;
        b1v[nt] = b1[u];
        phv[nt] = projh[b * NU + u];
        Vv[nt]  = V[u];
    }

    float (*partial)[128] = (float(*)[128])aT;   // reuse A LDS (post-barrier)
    #pragma unroll
    for (int mt = 0; mt < 8; ++mt) {
        #pragma unroll
        for (int rg = 0; rg < 4; ++rg) {
            float s = 0.f;
            #pragma unroll
            for (int nt = 0; nt < 4; ++nt) {
                float pv = acc[mt][nt][rg] + b1v[nt] + phv[nt];
                s += fast_tanh(pv) * Vv[nt];
            }
            s += __shfl_xor(s, 1);
            s += __shfl_xor(s, 2);
            s += __shfl_xor(s, 4);
            s += __shfl_xor(s, 8);
            if (col == 0) partial[wave][mt * 16 + quad * 4 + rg] = s;
        }
    }
    __syncthreads();
    if (tid < 128) {
        float v = partial[0][tid] + partial[1][tid] + partial[2][tid] + partial[3][tid];
        atomicAdd(&logits[row0 + tid], v);
    }
}

// ---- softmax over T per batch ----------------------------------------------
__global__ void k_softmax(const float* __restrict__ logits, float* __restrict__ attn) {
    int b = blockIdx.x, tid = threadIdx.x;   // 1024 threads
    __shared__ float wm[16], ws[16];
    const float* lg = logits + b * NT;
    float lv[2];
    float m = -1e30f;
    #pragma unroll
    for (int i = 0; i < 2; ++i) { lv[i] = lg[tid + i * 1024]; m = fmaxf(m, lv[i]); }
    for (int o = 1; o < 64; o <<= 1) m = fmaxf(m, __shfl_xor(m, o));
    if ((tid & 63) == 0) wm[tid >> 6] = m;
    __syncthreads();
    #pragma unroll
    for (int i = 0; i < 16; ++i) m = fmaxf(m, wm[i]);
    float ssum = 0.f, ev[2];
    #pragma unroll
    for (int i = 0; i < 2; ++i) { ev[i] = __expf(lv[i] - m); ssum += ev[i]; }
    for (int o = 1; o < 64; o <<= 1) ssum += __shfl_xor(ssum, o);
    if ((tid & 63) == 0) ws[tid >> 6] = ssum;
    __syncthreads();
    float tot = 0.f;
    #pragma unroll
    for (int i = 0; i < 16; ++i) tot += ws[i];
    float inv = 1.f / tot;
    #pragma unroll
    for (int i = 0; i < 2; ++i) attn[b * NT + tid + i * 1024] = ev[i] * inv;
}

// ---- context[b,d] = sum_t attn[b,t] * feat[b,t,d] --------------------------
__global__ void k_context(const float* __restrict__ feat, const float* __restrict__ attn,
                          float* __restrict__ ctx) {
    int b  = blockIdx.x >> 5;
    int tc = blockIdx.x & 31;
    const float* fb = feat + ((long)b * NT + tc * 64) * ND + threadIdx.x * 2;
    const float* ab = attn + b * NT + tc * 64;
    float ax = 0.f, ay = 0.f;
    #pragma unroll 16
    for (int t = 0; t < 64; ++t) {
        float a = ab[t];
        float2 f = *(const float2*)(fb + (long)t * ND);
        ax += a * f.x; ay += a * f.y;
    }
    atomicAdd(&ctx[b * ND + threadIdx.x * 2],     ax);
    atomicAdd(&ctx[b * ND + threadIdx.x * 2 + 1], ay);
}

extern "C" void kernel_launch(void* const* d_in, const int* in_sizes, int n_in,
                              void* d_out, int out_size, void* d_ws, size_t ws_size,
                              hipStream_t stream) {
    const float* feat   = (const float*)d_in[0];
    const float* hidden = (const float*)d_in[1];
    const float* W1     = (const float*)d_in[2];
    const float* b1     = (const float*)d_in[3];
    const float* W2     = (const float*)d_in[4];
    const float* b2     = (const float*)d_in[5];
    const float* V      = (const float*)d_in[6];
    // d_in[7] = bv: unused — softmax(x + bv) == softmax(x)

    float* out_ctx  = (float*)d_out;            // [32,512]
    float* out_attn = (float*)d_out + NB * ND;  // [32,2048,1]

    u16*   w1t    = (u16*)d_ws;                                          // 512 KB
    float* projh  = (float*)((char*)d_ws + 512 * 1024);                  // 64 KB
    float* logits = (float*)((char*)d_ws + 512 * 1024 + 64 * 1024);      // 256 KB

    k_setup  <<<512, 256, 0, stream>>>(W1, w1t, hidden, W2, b2, projh, logits, out_ctx);
    k_logits <<<1024, 256, 0, stream>>>(feat, w1t, b1, projh, V, logits);
    k_softmax<<<NB, 1024, 0, stream>>>(logits, out_attn);
    k_context<<<1024, 256, 0, stream>>>(feat, out_attn, out_ctx);
}